// Round 1
// baseline (546.477 us; speedup 1.0000x reference)
//
#include <hip/hip_runtime.h>
#include <stdint.h>
#include <math.h>

// Problem constants (from reference)
#define N_NODES   100000
#define N_EDGES   1600000
#define NFEAT     100
#define HIDDEN    32
#define OUTC      2

// ---------------------------------------------------------------------------
// JAX threefry2x32 with key = jax.random.key(42)  ->  (k1,k2) = (0, 42)
// Partitionable scheme (jax_threefry_partitionable=True, default in modern JAX):
//   for flat index f: (o0,o1) = threefry2x32((0,42), (hi=0, lo=f)); bits = o0^o1
// Uniform: u = bitcast((bits>>9)|0x3f800000) - 1.0 ;  keep = u < 0.8f
// ---------------------------------------------------------------------------
__device__ __forceinline__ uint32_t rotl32(uint32_t x, int r) {
    return (x << r) | (x >> (32 - r));
}

__device__ __forceinline__ uint32_t threefry_bits(uint32_t f) {
    const uint32_t ks0 = 0u;
    const uint32_t ks1 = 42u;
    const uint32_t ks2 = 0x1BD11BDAu ^ 0u ^ 42u;
    uint32_t x0 = 0u + ks0;   // counts1 (hi word) + ks[0]
    uint32_t x1 = f  + ks1;   // counts2 (lo word) + ks[1]
#define TF_ROUND(r) { x0 += x1; x1 = rotl32(x1, (r)); x1 ^= x0; }
    TF_ROUND(13) TF_ROUND(15) TF_ROUND(26) TF_ROUND(6)
    x0 += ks1; x1 += ks2 + 1u;
    TF_ROUND(17) TF_ROUND(29) TF_ROUND(16) TF_ROUND(24)
    x0 += ks2; x1 += ks0 + 2u;
    TF_ROUND(13) TF_ROUND(15) TF_ROUND(26) TF_ROUND(6)
    x0 += ks0; x1 += ks1 + 3u;
    TF_ROUND(17) TF_ROUND(29) TF_ROUND(16) TF_ROUND(24)
    x0 += ks1; x1 += ks2 + 4u;
    TF_ROUND(13) TF_ROUND(15) TF_ROUND(26) TF_ROUND(6)
    x0 += ks2; x1 += ks0 + 5u;
#undef TF_ROUND
    return x0 ^ x1;  // partitionable: xor of the two outputs
}

__device__ __forceinline__ bool dropout_keep(uint32_t f) {
    uint32_t bits = threefry_bits(f);
    float u = __uint_as_float((bits >> 9) | 0x3f800000u) - 1.0f;
    return u < 0.8f;
}

// ---------------------------------------------------------------------------
// Kernels
// ---------------------------------------------------------------------------

// Degree count over edge dst (int atomics; +1 self loop added in k_dinv)
__global__ __launch_bounds__(256) void k_deg(const int* __restrict__ dst,
                                             int* __restrict__ cnt) {
    int e = blockIdx.x * 256 + threadIdx.x;
    if (e < N_EDGES) atomicAdd(&cnt[dst[e]], 1);
}

__global__ __launch_bounds__(256) void k_dinv(const int* __restrict__ cnt,
                                              float* __restrict__ dinv) {
    int n = blockIdx.x * 256 + threadIdx.x;
    if (n < N_NODES) dinv[n] = 1.0f / sqrtf((float)(cnt[n] + 1));
}

// h0 = x @ W1   [N,100] @ [100,32] -> [N,32]; 8 rows per 256-thread block
__global__ __launch_bounds__(256) void k_gemm1(const float* __restrict__ x,
                                               const float* __restrict__ W1,
                                               float* __restrict__ h0) {
    __shared__ float w1s[NFEAT * HIDDEN];   // 3200 floats
    __shared__ float xs[8][NFEAT];          // 800 floats
    const int tid = threadIdx.x;
    for (int i = tid; i < NFEAT * HIDDEN; i += 256) w1s[i] = W1[i];
    const int row0 = blockIdx.x * 8;
    const float* xb = x + (size_t)row0 * NFEAT;
    for (int i = tid; i < 8 * NFEAT; i += 256) xs[i / NFEAT][i % NFEAT] = xb[i];
    __syncthreads();
    const int r = tid >> 5, c = tid & 31;
    float acc = 0.0f;
#pragma unroll 4
    for (int k = 0; k < NFEAT; ++k)
        acc = fmaf(xs[r][k], w1s[k * HIDDEN + c], acc);
    h0[(size_t)(row0 + r) * HIDDEN + c] = acc;
}

// Layer-1 edge aggregation: one thread per (edge, col)
__global__ __launch_bounds__(256) void k_agg1(const int* __restrict__ src,
                                              const int* __restrict__ dst,
                                              const float* __restrict__ dinv,
                                              const float* __restrict__ h0,
                                              float* __restrict__ agg1) {
    int t = blockIdx.x * 256 + threadIdx.x;   // < E*32 = 51.2M
    int e = t >> 5;
    int c = t & 31;
    if (e >= N_EDGES) return;
    int s = src[e], d = dst[e];
    float w = dinv[s] * dinv[d];
    atomicAdd(&agg1[(size_t)d * HIDDEN + c], h0[(size_t)s * HIDDEN + c] * w);
}

// Fused: self-loop + b1 + ReLU + dropout + (h1 @ W2) via shuffle reduction
__global__ __launch_bounds__(256) void k_post1(const float* __restrict__ agg1,
                                               const float* __restrict__ h0,
                                               const float* __restrict__ dinv,
                                               const float* __restrict__ b1,
                                               const float* __restrict__ W2,
                                               float* __restrict__ h2) {
    int t = blockIdx.x * 256 + threadIdx.x;   // flat index n*32 + c
    int n = t >> 5;
    int c = t & 31;
    if (n >= N_NODES) return;
    float di = dinv[n];
    float v = agg1[t] + h0[t] * di * di + b1[c];
    v = fmaxf(v, 0.0f);
    v = dropout_keep((uint32_t)t) ? v * 1.25f : 0.0f;  // /0.8 inverted scaling
    float p0 = v * W2[c * 2 + 0];
    float p1 = v * W2[c * 2 + 1];
#pragma unroll
    for (int m = 16; m >= 1; m >>= 1) {
        p0 += __shfl_xor(p0, m);
        p1 += __shfl_xor(p1, m);
    }
    if (c == 0) {
        h2[(size_t)n * 2 + 0] = p0;
        h2[(size_t)n * 2 + 1] = p1;
    }
}

// Layer-2 edge aggregation: one thread per edge, 2 atomics
__global__ __launch_bounds__(256) void k_agg2(const int* __restrict__ src,
                                              const int* __restrict__ dst,
                                              const float* __restrict__ dinv,
                                              const float* __restrict__ h2,
                                              float* __restrict__ agg2) {
    int e = blockIdx.x * 256 + threadIdx.x;
    if (e >= N_EDGES) return;
    int s = src[e], d = dst[e];
    float w = dinv[s] * dinv[d];
    atomicAdd(&agg2[(size_t)d * 2 + 0], h2[(size_t)s * 2 + 0] * w);
    atomicAdd(&agg2[(size_t)d * 2 + 1], h2[(size_t)s * 2 + 1] * w);
}

// Self-loop + b2 + log_softmax over 2 classes
__global__ __launch_bounds__(256) void k_final(const float* __restrict__ agg2,
                                               const float* __restrict__ h2,
                                               const float* __restrict__ dinv,
                                               const float* __restrict__ b2,
                                               float* __restrict__ out) {
    int n = blockIdx.x * 256 + threadIdx.x;
    if (n >= N_NODES) return;
    float di = dinv[n];
    float di2 = di * di;
    float l0 = agg2[(size_t)n * 2 + 0] + h2[(size_t)n * 2 + 0] * di2 + b2[0];
    float l1 = agg2[(size_t)n * 2 + 1] + h2[(size_t)n * 2 + 1] * di2 + b2[1];
    float m = fmaxf(l0, l1);
    float lse = m + logf(expf(l0 - m) + expf(l1 - m));
    out[(size_t)n * 2 + 0] = l0 - lse;
    out[(size_t)n * 2 + 1] = l1 - lse;
}

// ---------------------------------------------------------------------------
// Launch
// ---------------------------------------------------------------------------
static inline size_t align_up(size_t x) { return (x + 255) & ~(size_t)255; }

extern "C" void kernel_launch(void* const* d_in, const int* in_sizes, int n_in,
                              void* d_out, int out_size, void* d_ws, size_t ws_size,
                              hipStream_t stream) {
    (void)n_in; (void)in_sizes; (void)out_size; (void)ws_size;

    const float* x  = (const float*)d_in[0];
    const int*   ei = (const int*)d_in[1];     // edge_index [2, E] (int32 on device)
    const float* W1 = (const float*)d_in[2];
    const float* b1 = (const float*)d_in[3];
    const float* W2 = (const float*)d_in[4];
    const float* b2 = (const float*)d_in[5];
    float* out = (float*)d_out;

    const int* src = ei;
    const int* dst = ei + N_EDGES;

    // Workspace layout
    char* w = (char*)d_ws;
    size_t off = 0;
    int*   cnt  = (int*)(w + off);   off += align_up((size_t)N_NODES * 4);
    float* dinv = (float*)(w + off); off += align_up((size_t)N_NODES * 4);
    float* h0   = (float*)(w + off); off += align_up((size_t)N_NODES * HIDDEN * 4);
    float* agg1 = (float*)(w + off); off += align_up((size_t)N_NODES * HIDDEN * 4);
    float* h2   = (float*)(w + off); off += align_up((size_t)N_NODES * OUTC * 4);
    float* agg2 = (float*)(w + off); off += align_up((size_t)N_NODES * OUTC * 4);

    // Zero the accumulators (ws is re-poisoned to 0xAA before every launch)
    hipMemsetAsync(cnt,  0, (size_t)N_NODES * 4, stream);
    hipMemsetAsync(agg1, 0, (size_t)N_NODES * HIDDEN * 4, stream);
    hipMemsetAsync(agg2, 0, (size_t)N_NODES * OUTC * 4, stream);

    const int B = 256;
    k_deg  <<<(N_EDGES + B - 1) / B, B, 0, stream>>>(dst, cnt);
    k_dinv <<<(N_NODES + B - 1) / B, B, 0, stream>>>(cnt, dinv);
    k_gemm1<<<N_NODES / 8, B, 0, stream>>>(x, W1, h0);
    {
        long long tot = (long long)N_EDGES * HIDDEN;
        k_agg1<<<(int)((tot + B - 1) / B), B, 0, stream>>>(src, dst, dinv, h0, agg1);
    }
    k_post1<<<(N_NODES * HIDDEN) / B, B, 0, stream>>>(agg1, h0, dinv, b1, W2, h2);
    k_agg2 <<<(N_EDGES + B - 1) / B, B, 0, stream>>>(src, dst, dinv, h2, agg2);
    k_final<<<(N_NODES + B - 1) / B, B, 0, stream>>>(agg2, h2, dinv, b2, out);
}